// Round 1
// baseline (4513.742 us; speedup 1.0000x reference)
//
#include <hip/hip_runtime.h>

// MsgPassingNN: 3 rounds of edge-MLP + segment_sum + node-MLP.
// N=100000 nodes (D=16), E=3200000 edges.
// fe: 32 -> 9 (relu) -> 9 (relu) -> 9
// fx: 25 -> 9 (relu) -> 9 (relu) -> 16

constexpr int NN = 100000;
constexpr int NE = 3200000;

__global__ __launch_bounds__(256) void edge_k(
    const float* __restrict__ X,
    const int* __restrict__ src, const int* __restrict__ dst,
    const float* __restrict__ W1, const float* __restrict__ b1,
    const float* __restrict__ W2, const float* __restrict__ b2,
    const float* __restrict__ W3, const float* __restrict__ b3,
    float* __restrict__ m)
{
    __shared__ float sW1[288], sW2[81], sW3[81], sB[27];
    const int t = threadIdx.x;
    for (int i = t; i < 288; i += 256) sW1[i] = W1[i];
    if (t < 81) sW2[t] = W2[t];
    else if (t < 162) sW3[t - 81] = W3[t - 81];
    else if (t < 171) sB[t - 162] = b1[t - 162];
    else if (t < 180) sB[9 + t - 171] = b2[t - 171];
    else if (t < 189) sB[18 + t - 180] = b3[t - 180];
    __syncthreads();

    const int e = blockIdx.x * 256 + t;   // NE % 256 == 0, no tail
    const int vd = dst[e];
    const int vs = src[e];

    float x[32];
    {
        const float4* p = reinterpret_cast<const float4*>(X + (size_t)vd * 16);
        #pragma unroll
        for (int q = 0; q < 4; ++q) {
            float4 v = p[q];
            x[4*q+0] = v.x; x[4*q+1] = v.y; x[4*q+2] = v.z; x[4*q+3] = v.w;
        }
        p = reinterpret_cast<const float4*>(X + (size_t)vs * 16);
        #pragma unroll
        for (int q = 0; q < 4; ++q) {
            float4 v = p[q];
            x[16+4*q+0] = v.x; x[16+4*q+1] = v.y; x[16+4*q+2] = v.z; x[16+4*q+3] = v.w;
        }
    }

    float h1[9];
    #pragma unroll
    for (int j = 0; j < 9; ++j) h1[j] = sB[j];
    #pragma unroll
    for (int i = 0; i < 32; ++i) {
        const float xi = x[i];
        #pragma unroll
        for (int j = 0; j < 9; ++j) h1[j] = fmaf(xi, sW1[i*9 + j], h1[j]);
    }
    #pragma unroll
    for (int j = 0; j < 9; ++j) h1[j] = fmaxf(h1[j], 0.0f);

    float h2[9];
    #pragma unroll
    for (int j = 0; j < 9; ++j) h2[j] = sB[9 + j];
    #pragma unroll
    for (int i = 0; i < 9; ++i) {
        const float hi = h1[i];
        #pragma unroll
        for (int j = 0; j < 9; ++j) h2[j] = fmaf(hi, sW2[i*9 + j], h2[j]);
    }
    #pragma unroll
    for (int j = 0; j < 9; ++j) h2[j] = fmaxf(h2[j], 0.0f);

    float o[9];
    #pragma unroll
    for (int j = 0; j < 9; ++j) o[j] = sB[18 + j];
    #pragma unroll
    for (int i = 0; i < 9; ++i) {
        const float hi = h2[i];
        #pragma unroll
        for (int j = 0; j < 9; ++j) o[j] = fmaf(hi, sW3[i*9 + j], o[j]);
    }

    float* mp = m + (size_t)vd * 9;
    #pragma unroll
    for (int j = 0; j < 9; ++j) atomicAdd(mp + j, o[j]);
}

__global__ __launch_bounds__(256) void node_k(
    const float* __restrict__ Xin, const float* __restrict__ m,
    const float* __restrict__ W1, const float* __restrict__ b1,
    const float* __restrict__ W2, const float* __restrict__ b2,
    const float* __restrict__ W3, const float* __restrict__ b3,
    float* __restrict__ Xout)
{
    __shared__ float sW1[225], sW2[81], sW3[144], sB[34]; // b1(9) b2(9) b3(16)
    const int t = threadIdx.x;
    if (t < 225) sW1[t] = W1[t];
    if (t < 81)       sW2[t] = W2[t];
    else if (t < 225) sW3[t - 81] = W3[t - 81];
    if (t >= 225 && t < 234) sB[t - 225] = b1[t - 225];
    else if (t >= 234 && t < 243) sB[9 + t - 234] = b2[t - 234];
    else if (t >= 243 && t < 256 && (t - 243) < 16) sB[18 + t - 243] = b3[t - 243];
    // remaining b3 elements (16 > 13) — cover with t<3 extra
    if (t < 3) sB[18 + 13 + t] = b3[13 + t];
    __syncthreads();

    const int n = blockIdx.x * 256 + t;
    if (n >= NN) return;

    float x[25];
    {
        const float4* p = reinterpret_cast<const float4*>(Xin + (size_t)n * 16);
        #pragma unroll
        for (int q = 0; q < 4; ++q) {
            float4 v = p[q];
            x[4*q+0] = v.x; x[4*q+1] = v.y; x[4*q+2] = v.z; x[4*q+3] = v.w;
        }
        const float* mp = m + (size_t)n * 9;
        #pragma unroll
        for (int j = 0; j < 9; ++j) x[16 + j] = mp[j];
    }

    float h1[9];
    #pragma unroll
    for (int j = 0; j < 9; ++j) h1[j] = sB[j];
    #pragma unroll
    for (int i = 0; i < 25; ++i) {
        const float xi = x[i];
        #pragma unroll
        for (int j = 0; j < 9; ++j) h1[j] = fmaf(xi, sW1[i*9 + j], h1[j]);
    }
    #pragma unroll
    for (int j = 0; j < 9; ++j) h1[j] = fmaxf(h1[j], 0.0f);

    float h2[9];
    #pragma unroll
    for (int j = 0; j < 9; ++j) h2[j] = sB[9 + j];
    #pragma unroll
    for (int i = 0; i < 9; ++i) {
        const float hi = h1[i];
        #pragma unroll
        for (int j = 0; j < 9; ++j) h2[j] = fmaf(hi, sW2[i*9 + j], h2[j]);
    }
    #pragma unroll
    for (int j = 0; j < 9; ++j) h2[j] = fmaxf(h2[j], 0.0f);

    float o[16];
    #pragma unroll
    for (int k = 0; k < 16; ++k) o[k] = sB[18 + k];
    #pragma unroll
    for (int j = 0; j < 9; ++j) {
        const float hj = h2[j];
        #pragma unroll
        for (int k = 0; k < 16; ++k) o[k] = fmaf(hj, sW3[j*16 + k], o[k]);
    }

    float4* po = reinterpret_cast<float4*>(Xout + (size_t)n * 16);
    #pragma unroll
    for (int q = 0; q < 4; ++q) {
        float4 v;
        v.x = o[4*q+0]; v.y = o[4*q+1]; v.z = o[4*q+2]; v.w = o[4*q+3];
        po[q] = v;
    }
}

extern "C" void kernel_launch(void* const* d_in, const int* in_sizes, int n_in,
                              void* d_out, int out_size, void* d_ws, size_t ws_size,
                              hipStream_t stream)
{
    const float* X0   = (const float*)d_in[0];
    const int*   esrc = (const int*)d_in[1];
    const int*   edst = (const int*)d_in[2];
    const float* feW1 = (const float*)d_in[3];
    const float* feb1 = (const float*)d_in[4];
    const float* feW2 = (const float*)d_in[5];
    const float* feb2 = (const float*)d_in[6];
    const float* feW3 = (const float*)d_in[7];
    const float* feb3 = (const float*)d_in[8];
    const float* fxW1 = (const float*)d_in[9];
    const float* fxb1 = (const float*)d_in[10];
    const float* fxW2 = (const float*)d_in[11];
    const float* fxb2 = (const float*)d_in[12];
    const float* fxW3 = (const float*)d_in[13];
    const float* fxb3 = (const float*)d_in[14];

    float* out  = (float*)d_out;
    float* bufX = (float*)d_ws;                  // NN*16 floats
    float* mb   = bufX + (size_t)NN * 16;        // NN*9 floats

    const dim3 thr(256);
    const dim3 ge(NE / 256);
    const dim3 gn((NN + 255) / 256);
    const size_t mbytes = (size_t)NN * 9 * sizeof(float);

    // round 0: read d_in X, write bufX
    hipMemsetAsync(mb, 0, mbytes, stream);
    edge_k<<<ge, thr, 0, stream>>>(X0, esrc, edst, feW1, feb1, feW2, feb2, feW3, feb3, mb);
    node_k<<<gn, thr, 0, stream>>>(X0, mb, fxW1, fxb1, fxW2, fxb2, fxW3, fxb3, bufX);

    // round 1: in-place on bufX (node i reads only row i)
    hipMemsetAsync(mb, 0, mbytes, stream);
    edge_k<<<ge, thr, 0, stream>>>(bufX, esrc, edst, feW1, feb1, feW2, feb2, feW3, feb3, mb);
    node_k<<<gn, thr, 0, stream>>>(bufX, mb, fxW1, fxb1, fxW2, fxb2, fxW3, fxb3, bufX);

    // round 2: write final to d_out
    hipMemsetAsync(mb, 0, mbytes, stream);
    edge_k<<<ge, thr, 0, stream>>>(bufX, esrc, edst, feW1, feb1, feW2, feb2, feW3, feb3, mb);
    node_k<<<gn, thr, 0, stream>>>(bufX, mb, fxW1, fxb1, fxW2, fxb2, fxW3, fxb3, out);
}

// Round 2
// 805.585 us; speedup vs baseline: 5.6031x; 5.6031x over previous
//
#include <hip/hip_runtime.h>

// MsgPassingNN: 3 rounds of edge-MLP + segment_sum + node-MLP.
// N=100000 nodes (D=16), E=3200000 edges.
// fe: 32 -> 9 (relu) -> 9 (relu) -> 9 ; fx: 25 -> 9 (relu) -> 9 (relu) -> 16
//
// Strategy: build CSR (edges grouped by dst) once per launch, then 3 fused
// node-centric rounds: recompute messages inline per incoming edge (each msg
// consumed exactly once), accumulate in registers -> NO atomics in hot loop.

constexpr int NN = 100000;
constexpr int NE = 3200000;
constexpr int NB_CNT = (NN + 255) / 256;   // 391 blocks over node array

// ---------------- CSR build ----------------

__global__ __launch_bounds__(256) void hist_k(const int* __restrict__ dst,
                                              int* __restrict__ cnt,
                                              unsigned short* __restrict__ rank)
{
    int e = blockIdx.x * 256 + threadIdx.x;
    if (e >= NE) return;
    int d = dst[e];
    rank[e] = (unsigned short)atomicAdd(&cnt[d], 1);
}

__global__ __launch_bounds__(256) void blocksum_k(const int* __restrict__ cnt,
                                                  int* __restrict__ bsum)
{
    __shared__ int red[256];
    int t = threadIdx.x;
    int i = blockIdx.x * 256 + t;
    red[t] = (i < NN) ? cnt[i] : 0;
    __syncthreads();
    for (int off = 128; off > 0; off >>= 1) {
        if (t < off) red[t] += red[t + off];
        __syncthreads();
    }
    if (t == 0) bsum[blockIdx.x] = red[0];
}

__global__ __launch_bounds__(512) void scanpart_k(const int* __restrict__ bsum,
                                                  int* __restrict__ boff, int nb)
{
    __shared__ int s[512];
    int t = threadIdx.x;
    int v = (t < nb) ? bsum[t] : 0;
    s[t] = v;
    __syncthreads();
    for (int off = 1; off < 512; off <<= 1) {
        int a = (t >= off) ? s[t - off] : 0;
        __syncthreads();
        s[t] += a;
        __syncthreads();
    }
    if (t < nb) boff[t] = s[t] - v;   // exclusive
}

__global__ __launch_bounds__(256) void rowstart_k(const int* __restrict__ cnt,
                                                  const int* __restrict__ boff,
                                                  int* __restrict__ row_start)
{
    __shared__ int s[256];
    int t = threadIdx.x;
    int i = blockIdx.x * 256 + t;
    int v = (i < NN) ? cnt[i] : 0;
    s[t] = v;
    __syncthreads();
    for (int off = 1; off < 256; off <<= 1) {
        int a = (t >= off) ? s[t - off] : 0;
        __syncthreads();
        s[t] += a;
        __syncthreads();
    }
    int incl = s[t];
    if (i < NN) row_start[i] = boff[blockIdx.x] + incl - v;
    if (i == NN - 1) row_start[NN] = boff[blockIdx.x] + incl;
}

__global__ __launch_bounds__(256) void scatter_k(const int* __restrict__ src,
                                                 const int* __restrict__ dst,
                                                 const unsigned short* __restrict__ rank,
                                                 const int* __restrict__ row_start,
                                                 int* __restrict__ ssrc)
{
    int e = blockIdx.x * 256 + threadIdx.x;
    if (e >= NE) return;
    int d = dst[e];
    ssrc[row_start[d] + (int)rank[e]] = src[e];
}

// ---------------- fused round ----------------
// 2 threads per node (half = gid&1). Each thread walks its interleaved share
// of the node's incoming edges, 2 edges per iteration (shared LDS weight
// broadcasts). Pair-reduce via shfl_xor(1), half==0 does the node MLP.

__global__ __launch_bounds__(256) void fused_k(
    const float* __restrict__ Xin,
    const int* __restrict__ row_start,
    const int* __restrict__ ssrc,
    const float* __restrict__ feW1, const float* __restrict__ feb1,
    const float* __restrict__ feW2, const float* __restrict__ feb2,
    const float* __restrict__ feW3, const float* __restrict__ feb3,
    const float* __restrict__ fxW1, const float* __restrict__ fxb1,
    const float* __restrict__ fxW2, const float* __restrict__ fxb2,
    const float* __restrict__ fxW3, const float* __restrict__ fxb3,
    float* __restrict__ Xout)
{
    // padded leading dim 12 -> 16B-aligned rows for b128 LDS reads
    __shared__ float sW1[32 * 12], sW2[9 * 12], sW3[9 * 12], sEB[32];
    __shared__ float sU1[25 * 12], sU2[9 * 12], sU3[9 * 16], sNB[40];
    const int t = threadIdx.x;

    for (int i = t; i < 32 * 12; i += 256) sW1[i] = 0.f;
    for (int i = t; i < 9 * 12; i += 256) { sW2[i] = 0.f; sW3[i] = 0.f; sU2[i] = 0.f; }
    for (int i = t; i < 25 * 12; i += 256) sU1[i] = 0.f;
    __syncthreads();
    for (int i = t; i < 288; i += 256) sW1[(i / 9) * 12 + (i % 9)] = feW1[i];
    if (t < 81) {
        sW2[(t / 9) * 12 + (t % 9)] = feW2[t];
        sW3[(t / 9) * 12 + (t % 9)] = feW3[t];
        sU2[(t / 9) * 12 + (t % 9)] = fxW2[t];
    }
    if (t < 225) sU1[(t / 9) * 12 + (t % 9)] = fxW1[t];
    if (t < 144) sU3[t] = fxW3[t];
    if (t < 9)                sEB[t] = feb1[t];
    if (t >= 32 && t < 41)    sEB[9 + (t - 32)] = feb2[t - 32];
    if (t >= 64 && t < 73)    sEB[18 + (t - 64)] = feb3[t - 64];
    if (t >= 96 && t < 105)   sNB[t - 96] = fxb1[t - 96];
    if (t >= 128 && t < 137)  sNB[9 + (t - 128)] = fxb2[t - 128];
    if (t >= 160 && t < 176)  sNB[18 + (t - 160)] = fxb3[t - 160];
    __syncthreads();

    const int gid = blockIdx.x * 256 + t;
    const int n = gid >> 1;
    const int half = gid & 1;
    const bool active = (n < NN);

    float xr[16];
    int beg = 0, end = 0;
    if (active) {
        const float4* pr = reinterpret_cast<const float4*>(Xin + (size_t)n * 16);
        #pragma unroll
        for (int q = 0; q < 4; ++q) {
            float4 v = pr[q];
            xr[4*q] = v.x; xr[4*q+1] = v.y; xr[4*q+2] = v.z; xr[4*q+3] = v.w;
        }
        beg = row_start[n];
        end = row_start[n + 1];
    } else {
        #pragma unroll
        for (int q = 0; q < 16; ++q) xr[q] = 0.f;
    }

    // hoist the X[dst] half of fe layer-1 (node-invariant across this node's edges)
    float base1[9];
    #pragma unroll
    for (int j = 0; j < 9; ++j) base1[j] = sEB[j];
    #pragma unroll
    for (int i = 0; i < 16; ++i) {
        const float xi = xr[i];
        #pragma unroll
        for (int j = 0; j < 9; ++j) base1[j] = fmaf(xi, sW1[i * 12 + j], base1[j]);
    }

    float mm[9];
    #pragma unroll
    for (int j = 0; j < 9; ++j) mm[j] = 0.f;

    int p = beg + half;
    // dual-edge main loop: edges p and p+2 (this thread's stride-2 share)
    for (; p + 2 < end; p += 4) {
        const int s0 = ssrc[p];
        const int s1 = ssrc[p + 2];
        float xs0[16], xs1[16];
        {
            const float4* p0 = reinterpret_cast<const float4*>(Xin + (size_t)s0 * 16);
            const float4* p1 = reinterpret_cast<const float4*>(Xin + (size_t)s1 * 16);
            #pragma unroll
            for (int q = 0; q < 4; ++q) {
                float4 v = p0[q];
                xs0[4*q] = v.x; xs0[4*q+1] = v.y; xs0[4*q+2] = v.z; xs0[4*q+3] = v.w;
            }
            #pragma unroll
            for (int q = 0; q < 4; ++q) {
                float4 v = p1[q];
                xs1[4*q] = v.x; xs1[4*q+1] = v.y; xs1[4*q+2] = v.z; xs1[4*q+3] = v.w;
            }
        }
        float a0[9], a1[9];
        #pragma unroll
        for (int j = 0; j < 9; ++j) { a0[j] = base1[j]; a1[j] = base1[j]; }
        #pragma unroll
        for (int i = 0; i < 16; ++i) {
            const float x0 = xs0[i], x1 = xs1[i];
            #pragma unroll
            for (int j = 0; j < 9; ++j) {
                const float w = sW1[(16 + i) * 12 + j];
                a0[j] = fmaf(x0, w, a0[j]);
                a1[j] = fmaf(x1, w, a1[j]);
            }
        }
        #pragma unroll
        for (int j = 0; j < 9; ++j) { a0[j] = fmaxf(a0[j], 0.f); a1[j] = fmaxf(a1[j], 0.f); }

        float c0[9], c1[9];
        #pragma unroll
        for (int j = 0; j < 9; ++j) { c0[j] = sEB[9 + j]; c1[j] = sEB[9 + j]; }
        #pragma unroll
        for (int i = 0; i < 9; ++i) {
            const float x0 = a0[i], x1 = a1[i];
            #pragma unroll
            for (int j = 0; j < 9; ++j) {
                const float w = sW2[i * 12 + j];
                c0[j] = fmaf(x0, w, c0[j]);
                c1[j] = fmaf(x1, w, c1[j]);
            }
        }
        #pragma unroll
        for (int j = 0; j < 9; ++j) { c0[j] = fmaxf(c0[j], 0.f); c1[j] = fmaxf(c1[j], 0.f); }

        #pragma unroll
        for (int j = 0; j < 9; ++j) mm[j] += 2.f * sEB[18 + j];
        #pragma unroll
        for (int i = 0; i < 9; ++i) {
            const float x0 = c0[i], x1 = c1[i];
            #pragma unroll
            for (int j = 0; j < 9; ++j) {
                const float w = sW3[i * 12 + j];
                mm[j] = fmaf(x0, w, mm[j]);
                mm[j] = fmaf(x1, w, mm[j]);
            }
        }
    }
    // tail: at most one edge left for this thread
    if (p < end) {
        const int s0 = ssrc[p];
        float xs0[16];
        const float4* p0 = reinterpret_cast<const float4*>(Xin + (size_t)s0 * 16);
        #pragma unroll
        for (int q = 0; q < 4; ++q) {
            float4 v = p0[q];
            xs0[4*q] = v.x; xs0[4*q+1] = v.y; xs0[4*q+2] = v.z; xs0[4*q+3] = v.w;
        }
        float a0[9];
        #pragma unroll
        for (int j = 0; j < 9; ++j) a0[j] = base1[j];
        #pragma unroll
        for (int i = 0; i < 16; ++i) {
            const float x0 = xs0[i];
            #pragma unroll
            for (int j = 0; j < 9; ++j) a0[j] = fmaf(x0, sW1[(16 + i) * 12 + j], a0[j]);
        }
        #pragma unroll
        for (int j = 0; j < 9; ++j) a0[j] = fmaxf(a0[j], 0.f);
        float c0[9];
        #pragma unroll
        for (int j = 0; j < 9; ++j) c0[j] = sEB[9 + j];
        #pragma unroll
        for (int i = 0; i < 9; ++i) {
            const float x0 = a0[i];
            #pragma unroll
            for (int j = 0; j < 9; ++j) c0[j] = fmaf(x0, sW2[i * 12 + j], c0[j]);
        }
        #pragma unroll
        for (int j = 0; j < 9; ++j) c0[j] = fmaxf(c0[j], 0.f);
        #pragma unroll
        for (int j = 0; j < 9; ++j) mm[j] += sEB[18 + j];
        #pragma unroll
        for (int i = 0; i < 9; ++i) {
            const float x0 = c0[i];
            #pragma unroll
            for (int j = 0; j < 9; ++j) mm[j] = fmaf(x0, sW3[i * 12 + j], mm[j]);
        }
    }

    // pair reduction (lanes 2k / 2k+1)
    #pragma unroll
    for (int j = 0; j < 9; ++j) mm[j] += __shfl_xor(mm[j], 1);

    if (active && half == 0) {
        // node MLP: input = [xr(16), mm(9)]
        float h1[9];
        #pragma unroll
        for (int j = 0; j < 9; ++j) h1[j] = sNB[j];
        #pragma unroll
        for (int i = 0; i < 16; ++i) {
            const float xi = xr[i];
            #pragma unroll
            for (int j = 0; j < 9; ++j) h1[j] = fmaf(xi, sU1[i * 12 + j], h1[j]);
        }
        #pragma unroll
        for (int i = 0; i < 9; ++i) {
            const float xi = mm[i];
            #pragma unroll
            for (int j = 0; j < 9; ++j) h1[j] = fmaf(xi, sU1[(16 + i) * 12 + j], h1[j]);
        }
        #pragma unroll
        for (int j = 0; j < 9; ++j) h1[j] = fmaxf(h1[j], 0.f);

        float h2[9];
        #pragma unroll
        for (int j = 0; j < 9; ++j) h2[j] = sNB[9 + j];
        #pragma unroll
        for (int i = 0; i < 9; ++i) {
            const float xi = h1[i];
            #pragma unroll
            for (int j = 0; j < 9; ++j) h2[j] = fmaf(xi, sU2[i * 12 + j], h2[j]);
        }
        #pragma unroll
        for (int j = 0; j < 9; ++j) h2[j] = fmaxf(h2[j], 0.f);

        float o[16];
        #pragma unroll
        for (int k = 0; k < 16; ++k) o[k] = sNB[18 + k];
        #pragma unroll
        for (int j = 0; j < 9; ++j) {
            const float hj = h2[j];
            #pragma unroll
            for (int k = 0; k < 16; ++k) o[k] = fmaf(hj, sU3[j * 16 + k], o[k]);
        }
        float4* po = reinterpret_cast<float4*>(Xout + (size_t)n * 16);
        #pragma unroll
        for (int q = 0; q < 4; ++q) {
            float4 v;
            v.x = o[4*q]; v.y = o[4*q+1]; v.z = o[4*q+2]; v.w = o[4*q+3];
            po[q] = v;
        }
    }
}

extern "C" void kernel_launch(void* const* d_in, const int* in_sizes, int n_in,
                              void* d_out, int out_size, void* d_ws, size_t ws_size,
                              hipStream_t stream)
{
    const float* X0   = (const float*)d_in[0];
    const int*   esrc = (const int*)d_in[1];
    const int*   edst = (const int*)d_in[2];
    const float* feW1 = (const float*)d_in[3];
    const float* feb1 = (const float*)d_in[4];
    const float* feW2 = (const float*)d_in[5];
    const float* feb2 = (const float*)d_in[6];
    const float* feW3 = (const float*)d_in[7];
    const float* feb3 = (const float*)d_in[8];
    const float* fxW1 = (const float*)d_in[9];
    const float* fxb1 = (const float*)d_in[10];
    const float* fxW2 = (const float*)d_in[11];
    const float* fxb2 = (const float*)d_in[12];
    const float* fxW3 = (const float*)d_in[13];
    const float* fxb3 = (const float*)d_in[14];
    float* out = (float*)d_out;

    // workspace layout (~26.5 MB)
    float* Xa = (float*)d_ws;                               // NN*16 floats
    int* cnt = (int*)(Xa + (size_t)NN * 16);                // NN
    int* row_start = cnt + NN;                              // NN+1
    int* bsum = row_start + (NN + 1);                       // NB_CNT
    int* boff = bsum + NB_CNT;                              // NB_CNT
    unsigned short* rank = (unsigned short*)(boff + NB_CNT);// NE u16
    int* ssrc = (int*)(rank + NE);                          // NE

    const dim3 thr(256);
    const dim3 gE(NE / 256);          // 12500
    const dim3 gC(NB_CNT);            // 391
    const dim3 gF((2 * NN + 255) / 256); // 782

    // ---- CSR build (once per launch) ----
    hipMemsetAsync(cnt, 0, (size_t)NN * sizeof(int), stream);
    hist_k<<<gE, thr, 0, stream>>>(edst, cnt, rank);
    blocksum_k<<<gC, thr, 0, stream>>>(cnt, bsum);
    scanpart_k<<<1, 512, 0, stream>>>(bsum, boff, NB_CNT);
    rowstart_k<<<gC, thr, 0, stream>>>(cnt, boff, row_start);
    scatter_k<<<gE, thr, 0, stream>>>(esrc, edst, rank, row_start, ssrc);

    // ---- 3 fused rounds (ping-pong: X0 -> out -> Xa -> out) ----
    fused_k<<<gF, thr, 0, stream>>>(X0, row_start, ssrc,
        feW1, feb1, feW2, feb2, feW3, feb3,
        fxW1, fxb1, fxW2, fxb2, fxW3, fxb3, out);
    fused_k<<<gF, thr, 0, stream>>>(out, row_start, ssrc,
        feW1, feb1, feW2, feb2, feW3, feb3,
        fxW1, fxb1, fxW2, fxb2, fxW3, fxb3, Xa);
    fused_k<<<gF, thr, 0, stream>>>(Xa, row_start, ssrc,
        feW1, feb1, feW2, feb2, feW3, feb3,
        fxW1, fxb1, fxW2, fxb2, fxW3, fxb3, out);
}

// Round 3
// 574.518 us; speedup vs baseline: 7.8566x; 1.4022x over previous
//
#include <hip/hip_runtime.h>

// MsgPassingNN: 3 rounds of edge-MLP + segment_sum + node-MLP.
// N=100000 nodes (D=16), E=3200000 edges.
// fe: 32 -> 9 (relu) -> 9 (relu) -> 9 ; fx: 25 -> 9 (relu) -> 9 (relu) -> 16
//
// R2 structure:
//   - CSR build once (hist+scan+scatter) -> edges sorted by dst, packed (dst,src) u64.
//   - Per round: edge-parallel kernel (1 thread/edge, perfect balance), messages
//     reduced in-wave via segmented scan (sorted by dst), tail lanes atomicAdd to m
//     (~1.3M atomics vs 28.8M naive). Node kernel applies fx, zeroes m for next
//     round, and precomputes base1 = W1_dst^T x + b1 (hoists 144 of 450 edge FMAs).

constexpr int NN = 100000;
constexpr int NE = 3200000;
constexpr int NB_CNT = (NN + 255) / 256;   // 391

// ---------------- CSR build ----------------

__global__ __launch_bounds__(256) void hist_k(const int* __restrict__ dst,
                                              int* __restrict__ cnt,
                                              unsigned short* __restrict__ rank)
{
    int e = blockIdx.x * 256 + threadIdx.x;
    if (e >= NE) return;
    int d = dst[e];
    rank[e] = (unsigned short)atomicAdd(&cnt[d], 1);
}

__global__ __launch_bounds__(256) void blocksum_k(const int* __restrict__ cnt,
                                                  int* __restrict__ bsum)
{
    __shared__ int red[256];
    int t = threadIdx.x;
    int i = blockIdx.x * 256 + t;
    red[t] = (i < NN) ? cnt[i] : 0;
    __syncthreads();
    for (int off = 128; off > 0; off >>= 1) {
        if (t < off) red[t] += red[t + off];
        __syncthreads();
    }
    if (t == 0) bsum[blockIdx.x] = red[0];
}

__global__ __launch_bounds__(512) void scanpart_k(const int* __restrict__ bsum,
                                                  int* __restrict__ boff, int nb)
{
    __shared__ int s[512];
    int t = threadIdx.x;
    int v = (t < nb) ? bsum[t] : 0;
    s[t] = v;
    __syncthreads();
    for (int off = 1; off < 512; off <<= 1) {
        int a = (t >= off) ? s[t - off] : 0;
        __syncthreads();
        s[t] += a;
        __syncthreads();
    }
    if (t < nb) boff[t] = s[t] - v;   // exclusive
}

__global__ __launch_bounds__(256) void rowstart_k(const int* __restrict__ cnt,
                                                  const int* __restrict__ boff,
                                                  int* __restrict__ row_start)
{
    __shared__ int s[256];
    int t = threadIdx.x;
    int i = blockIdx.x * 256 + t;
    int v = (i < NN) ? cnt[i] : 0;
    s[t] = v;
    __syncthreads();
    for (int off = 1; off < 256; off <<= 1) {
        int a = (t >= off) ? s[t - off] : 0;
        __syncthreads();
        s[t] += a;
        __syncthreads();
    }
    int incl = s[t];
    if (i < NN) row_start[i] = boff[blockIdx.x] + incl - v;
    if (i == NN - 1) row_start[NN] = boff[blockIdx.x] + incl;
}

__global__ __launch_bounds__(256) void scatter_k(const int* __restrict__ src,
                                                 const int* __restrict__ dst,
                                                 const unsigned short* __restrict__ rank,
                                                 const int* __restrict__ row_start,
                                                 unsigned long long* __restrict__ sed)
{
    int e = blockIdx.x * 256 + threadIdx.x;
    if (e >= NE) return;
    int d = dst[e];
    int pos = row_start[d] + (int)rank[e];
    sed[pos] = ((unsigned long long)(unsigned)d << 32) | (unsigned)src[e];
}

// ---------------- round-0 prologue: base1 from X0, zero m ----------------

__global__ __launch_bounds__(256) void base_k(const float* __restrict__ X,
                                              const float* __restrict__ feW1,
                                              const float* __restrict__ feb1,
                                              float* __restrict__ base1,
                                              float* __restrict__ m)
{
    __shared__ float sW[16 * 12], sb[9];
    const int t = threadIdx.x;
    if (t < 144) sW[(t / 9) * 12 + (t % 9)] = feW1[t];
    if (t < 9) sb[t] = feb1[t];
    __syncthreads();

    const int n = blockIdx.x * 256 + t;
    if (n >= NN) return;

    float x[16];
    const float4* p = reinterpret_cast<const float4*>(X + (size_t)n * 16);
    #pragma unroll
    for (int q = 0; q < 4; ++q) {
        float4 v = p[q];
        x[4*q] = v.x; x[4*q+1] = v.y; x[4*q+2] = v.z; x[4*q+3] = v.w;
    }
    float b[9];
    #pragma unroll
    for (int j = 0; j < 9; ++j) b[j] = sb[j];
    #pragma unroll
    for (int i = 0; i < 16; ++i) {
        const float xi = x[i];
        #pragma unroll
        for (int j = 0; j < 9; ++j) b[j] = fmaf(xi, sW[i * 12 + j], b[j]);
    }
    float* bp = base1 + (size_t)n * 12;
    #pragma unroll
    for (int j = 0; j < 9; ++j) bp[j] = b[j];
    float* mp = m + (size_t)n * 9;
    #pragma unroll
    for (int j = 0; j < 9; ++j) mp[j] = 0.f;
}

// ---------------- edge round: 1 thread / sorted edge ----------------

__global__ __launch_bounds__(256) void edge2_k(
    const float* __restrict__ X,
    const float* __restrict__ base1,
    const unsigned long long* __restrict__ sed,
    const float* __restrict__ feW1,
    const float* __restrict__ feW2, const float* __restrict__ feb2,
    const float* __restrict__ feW3, const float* __restrict__ feb3,
    float* __restrict__ m)
{
    __shared__ float sW1s[16 * 12], sW2[9 * 12], sW3[9 * 12], sb2[9], sb3[9];
    const int t = threadIdx.x;
    if (t < 144) sW1s[(t / 9) * 12 + (t % 9)] = feW1[144 + t];   // src-half rows 16..31
    if (t < 81)  sW2[(t / 9) * 12 + (t % 9)] = feW2[t];
    if (t >= 128 && t < 209) { int i = t - 128; sW3[(i / 9) * 12 + (i % 9)] = feW3[i]; }
    if (t >= 224 && t < 233) sb2[t - 224] = feb2[t - 224];
    if (t >= 240 && t < 249) sb3[t - 240] = feb3[t - 240];
    __syncthreads();

    const int e = blockIdx.x * 256 + t;          // NE % 256 == 0
    const unsigned long long pk = sed[e];
    const int d = (int)(pk >> 32);
    const int s = (int)(pk & 0xffffffffu);

    // dst-side hoisted partial (9 floats, 36B, L1-friendly: runs share d)
    float a[9];
    {
        const float4* pb = reinterpret_cast<const float4*>(base1 + (size_t)d * 12);
        float4 b0 = pb[0], b1 = pb[1];
        a[0] = b0.x; a[1] = b0.y; a[2] = b0.z; a[3] = b0.w;
        a[4] = b1.x; a[5] = b1.y; a[6] = b1.z; a[7] = b1.w;
        a[8] = base1[(size_t)d * 12 + 8];
    }
    float xs[16];
    {
        const float4* p0 = reinterpret_cast<const float4*>(X + (size_t)s * 16);
        #pragma unroll
        for (int q = 0; q < 4; ++q) {
            float4 v = p0[q];
            xs[4*q] = v.x; xs[4*q+1] = v.y; xs[4*q+2] = v.z; xs[4*q+3] = v.w;
        }
    }

    #pragma unroll
    for (int i = 0; i < 16; ++i) {
        const float xi = xs[i];
        #pragma unroll
        for (int j = 0; j < 9; ++j) a[j] = fmaf(xi, sW1s[i * 12 + j], a[j]);
    }
    #pragma unroll
    for (int j = 0; j < 9; ++j) a[j] = fmaxf(a[j], 0.f);

    float h2[9];
    #pragma unroll
    for (int j = 0; j < 9; ++j) h2[j] = sb2[j];
    #pragma unroll
    for (int i = 0; i < 9; ++i) {
        const float ai = a[i];
        #pragma unroll
        for (int j = 0; j < 9; ++j) h2[j] = fmaf(ai, sW2[i * 12 + j], h2[j]);
    }
    #pragma unroll
    for (int j = 0; j < 9; ++j) h2[j] = fmaxf(h2[j], 0.f);

    float o[9];
    #pragma unroll
    for (int j = 0; j < 9; ++j) o[j] = sb3[j];
    #pragma unroll
    for (int i = 0; i < 9; ++i) {
        const float hi = h2[i];
        #pragma unroll
        for (int j = 0; j < 9; ++j) o[j] = fmaf(hi, sW3[i * 12 + j], o[j]);
    }

    // segmented inclusive scan by d over the 64-lane wave (d sorted)
    const int lane = t & 63;
    #pragma unroll
    for (int off = 1; off < 64; off <<= 1) {
        const int od = __shfl_up(d, off);
        const bool ok = (lane >= off) && (od == d);
        #pragma unroll
        for (int j = 0; j < 9; ++j) {
            const float ov = __shfl_up(o[j], off);
            o[j] += ok ? ov : 0.f;
        }
    }
    const int dn = __shfl_down(d, 1);
    if (lane == 63 || dn != d) {                 // segment tail
        float* mp = m + (size_t)d * 9;
        #pragma unroll
        for (int j = 0; j < 9; ++j) atomicAdd(mp + j, o[j]);
    }
}

// ---------------- node round: fx MLP + zero m + next base1 ----------------

__global__ __launch_bounds__(256) void node2_k(
    const float* __restrict__ Xin, float* __restrict__ m,
    const float* __restrict__ fxW1, const float* __restrict__ fxb1,
    const float* __restrict__ fxW2, const float* __restrict__ fxb2,
    const float* __restrict__ fxW3, const float* __restrict__ fxb3,
    const float* __restrict__ feW1, const float* __restrict__ feb1,
    float* __restrict__ Xout, float* __restrict__ base1out)
{
    __shared__ float sU1[25 * 12], sU2[9 * 12], sU3[9 * 16], sW1d[16 * 12];
    __shared__ float sNB[34], sEB1[9];
    const int t = threadIdx.x;
    if (t < 225) sU1[(t / 9) * 12 + (t % 9)] = fxW1[t];
    if (t < 81)  sU2[(t / 9) * 12 + (t % 9)] = fxW2[t];
    if (t < 144) sU3[t] = fxW3[t];
    if (t < 144) sW1d[(t / 9) * 12 + (t % 9)] = feW1[t];
    if (t < 9) sNB[t] = fxb1[t];
    if (t >= 32 && t < 41) sNB[9 + (t - 32)] = fxb2[t - 32];
    if (t >= 64 && t < 80) sNB[18 + (t - 64)] = fxb3[t - 64];
    if (t >= 96 && t < 105) sEB1[t - 96] = feb1[t - 96];
    __syncthreads();

    const int n = blockIdx.x * 256 + t;
    if (n >= NN) return;

    float xr[16];
    {
        const float4* p = reinterpret_cast<const float4*>(Xin + (size_t)n * 16);
        #pragma unroll
        for (int q = 0; q < 4; ++q) {
            float4 v = p[q];
            xr[4*q] = v.x; xr[4*q+1] = v.y; xr[4*q+2] = v.z; xr[4*q+3] = v.w;
        }
    }
    float mm[9];
    float* mp = m + (size_t)n * 9;
    #pragma unroll
    for (int j = 0; j < 9; ++j) mm[j] = mp[j];
    #pragma unroll
    for (int j = 0; j < 9; ++j) mp[j] = 0.f;     // ready for next round

    float h1[9];
    #pragma unroll
    for (int j = 0; j < 9; ++j) h1[j] = sNB[j];
    #pragma unroll
    for (int i = 0; i < 16; ++i) {
        const float xi = xr[i];
        #pragma unroll
        for (int j = 0; j < 9; ++j) h1[j] = fmaf(xi, sU1[i * 12 + j], h1[j]);
    }
    #pragma unroll
    for (int i = 0; i < 9; ++i) {
        const float xi = mm[i];
        #pragma unroll
        for (int j = 0; j < 9; ++j) h1[j] = fmaf(xi, sU1[(16 + i) * 12 + j], h1[j]);
    }
    #pragma unroll
    for (int j = 0; j < 9; ++j) h1[j] = fmaxf(h1[j], 0.f);

    float h2[9];
    #pragma unroll
    for (int j = 0; j < 9; ++j) h2[j] = sNB[9 + j];
    #pragma unroll
    for (int i = 0; i < 9; ++i) {
        const float xi = h1[i];
        #pragma unroll
        for (int j = 0; j < 9; ++j) h2[j] = fmaf(xi, sU2[i * 12 + j], h2[j]);
    }
    #pragma unroll
    for (int j = 0; j < 9; ++j) h2[j] = fmaxf(h2[j], 0.f);

    float o[16];
    #pragma unroll
    for (int k = 0; k < 16; ++k) o[k] = sNB[18 + k];
    #pragma unroll
    for (int j = 0; j < 9; ++j) {
        const float hj = h2[j];
        #pragma unroll
        for (int k = 0; k < 16; ++k) o[k] = fmaf(hj, sU3[j * 16 + k], o[k]);
    }

    float4* po = reinterpret_cast<float4*>(Xout + (size_t)n * 16);
    #pragma unroll
    for (int q = 0; q < 4; ++q) {
        float4 v;
        v.x = o[4*q]; v.y = o[4*q+1]; v.z = o[4*q+2]; v.w = o[4*q+3];
        po[q] = v;
    }

    // base1 for NEXT round's edge kernel: W1_dst^T * X_new + b1
    float b[9];
    #pragma unroll
    for (int j = 0; j < 9; ++j) b[j] = sEB1[j];
    #pragma unroll
    for (int i = 0; i < 16; ++i) {
        const float xi = o[i];
        #pragma unroll
        for (int j = 0; j < 9; ++j) b[j] = fmaf(xi, sW1d[i * 12 + j], b[j]);
    }
    float* bp = base1out + (size_t)n * 12;
    #pragma unroll
    for (int j = 0; j < 9; ++j) bp[j] = b[j];
}

extern "C" void kernel_launch(void* const* d_in, const int* in_sizes, int n_in,
                              void* d_out, int out_size, void* d_ws, size_t ws_size,
                              hipStream_t stream)
{
    const float* X0   = (const float*)d_in[0];
    const int*   esrc = (const int*)d_in[1];
    const int*   edst = (const int*)d_in[2];
    const float* feW1 = (const float*)d_in[3];
    const float* feb1 = (const float*)d_in[4];
    const float* feW2 = (const float*)d_in[5];
    const float* feb2 = (const float*)d_in[6];
    const float* feW3 = (const float*)d_in[7];
    const float* feb3 = (const float*)d_in[8];
    const float* fxW1 = (const float*)d_in[9];
    const float* fxb1 = (const float*)d_in[10];
    const float* fxW2 = (const float*)d_in[11];
    const float* fxb2 = (const float*)d_in[12];
    const float* fxW3 = (const float*)d_in[13];
    const float* fxb3 = (const float*)d_in[14];
    float* out = (float*)d_out;

    // workspace layout (4B units). rank overlays {base1,m}: rank is dead after
    // scatter_k, base1/m are first written by base_k which runs after scatter_k.
    float* Xa        = (float*)d_ws;                          // 1,600,000
    int*   cnt       = (int*)(Xa + (size_t)NN * 16);          // 100,000
    int*   row_start = cnt + NN;                              // 100,002 (padded)
    int*   bsum      = row_start + (NN + 2);                  // 392
    int*   boff      = bsum + (NB_CNT + 1);                   // 392
    float* base1     = (float*)(boff + (NB_CNT + 1));         // union start
    float* mb        = base1 + (size_t)NN * 12;               // NN*9
    unsigned short* rank = (unsigned short*)base1;            // NE u16 (overlay)
    unsigned long long* sed =
        (unsigned long long*)(mb + (size_t)NN * 9);           // NE u64

    const dim3 thr(256);
    const dim3 gE(NE / 256);     // 12500
    const dim3 gN(NB_CNT);       // 391

    // ---- CSR build (once per launch) ----
    hipMemsetAsync(cnt, 0, (size_t)NN * sizeof(int), stream);
    hist_k<<<gE, thr, 0, stream>>>(edst, cnt, rank);
    blocksum_k<<<gN, thr, 0, stream>>>(cnt, bsum);
    scanpart_k<<<1, 512, 0, stream>>>(bsum, boff, NB_CNT);
    rowstart_k<<<gN, thr, 0, stream>>>(cnt, boff, row_start);
    scatter_k<<<gE, thr, 0, stream>>>(esrc, edst, rank, row_start, sed);

    // ---- round 0 ----
    base_k<<<gN, thr, 0, stream>>>(X0, feW1, feb1, base1, mb);
    edge2_k<<<gE, thr, 0, stream>>>(X0, base1, sed, feW1, feW2, feb2, feW3, feb3, mb);
    node2_k<<<gN, thr, 0, stream>>>(X0, mb, fxW1, fxb1, fxW2, fxb2, fxW3, fxb3,
                                    feW1, feb1, Xa, base1);
    // ---- round 1 ----
    edge2_k<<<gE, thr, 0, stream>>>(Xa, base1, sed, feW1, feW2, feb2, feW3, feb3, mb);
    node2_k<<<gN, thr, 0, stream>>>(Xa, mb, fxW1, fxb1, fxW2, fxb2, fxW3, fxb3,
                                    feW1, feb1, out, base1);
    // ---- round 2 ----
    edge2_k<<<gE, thr, 0, stream>>>(out, base1, sed, feW1, feW2, feb2, feW3, feb3, mb);
    node2_k<<<gN, thr, 0, stream>>>(out, mb, fxW1, fxb1, fxW2, fxb2, fxW3, fxb3,
                                    feW1, feb1, Xa, base1);

    // final X lives in Xa (round-2 node output) -> copy to out
    hipMemcpyAsync(out, Xa, (size_t)NN * 16 * sizeof(float),
                   hipMemcpyDeviceToDevice, stream);
}